// Round 21
// baseline (77.481 us; speedup 1.0000x reference)
//
#include <hip/hip_runtime.h>

// QuantizedConv2d: N=32, CIN=128, H=W=56, COUT=256, 3x3, pad=1 (zp=-3), stride 1.
// Round 21: combine the two confirmed-positive elements, which were never
// tested together: (1) r17's 32x32x32 MFMA core (halves LDS reads/op; 64px x
// 256cout blocks kill 4x cout staging redundancy) + (2) r20's LDS-transpose
// NONTEMPORAL epilogue (full-line contiguous runs; r17's gain was masked by
// its scattered stores, nt's gain was masked by r15's compute). Epilogue:
// 2 passes x 128 couts, XOR-swizzled 32KB buffer (2-way banks both phases).

typedef __attribute__((ext_vector_type(4))) int i32x4;
typedef __attribute__((ext_vector_type(16))) int i32x16;

#define NB_N 32
#define CIN 128
#define HH 56
#define WW 56
#define PH 58                              // padded H/W
#define COUT 256
#define PIX_PER_IMG (HH*WW)                // 3136
#define X_IMG_INTS (PIX_PER_IMG*CIN)
#define XP_ROW_BYTES (PH*CIN)              // 7424
#define XP_IMG_BYTES (PH*XP_ROW_BYTES)     // 430592
#define XQ_PAD_BYTES ((size_t)NB_N*XP_IMG_BYTES)
#define A4_BYTES (4*XP_ROW_BYTES)          // 29696 (4 halo rows)
#define LDS_BYTES 32768                    // max(A4, epilogue 128x64 ints)

// ---------------- pack_x: NCHW int32 -> padded NHWC int8 (+ fused halo) ----------------
#define WPR 33   // words per w-row (132 B)
__global__ __launch_bounds__(256) void pack_x_kernel(const int* __restrict__ x,
                                                     signed char* __restrict__ xq) {
    __shared__ int tile[WW * WPR];           // 7392 B
    int nh = blockIdx.x;                     // 0..N*H-1
    int n = nh / HH, h = nh - n * HH;
    const int* src = x + (size_t)n * X_IMG_INTS + h * WW;  // (n, c, h, 0)
    signed char* img = xq + (size_t)n * XP_IMG_BYTES;
    int q = threadIdx.x & 15;                // w-quad (0..13 valid)
    int cg4 = threadIdx.x >> 4;              // 0..15
    if (q < 14) {
#pragma unroll
        for (int i = 0; i < 2; ++i) {
            int cg = cg4 + i * 16;           // channel group 0..31
            i32x4 v0 = *(const i32x4*)(src + (cg * 4 + 0) * PIX_PER_IMG + q * 4);
            i32x4 v1 = *(const i32x4*)(src + (cg * 4 + 1) * PIX_PER_IMG + q * 4);
            i32x4 v2 = *(const i32x4*)(src + (cg * 4 + 2) * PIX_PER_IMG + q * 4);
            i32x4 v3 = *(const i32x4*)(src + (cg * 4 + 3) * PIX_PER_IMG + q * 4);
#pragma unroll
            for (int j = 0; j < 4; ++j) {
                int word = (v0[j] & 255) | ((v1[j] & 255) << 8) |
                           ((v2[j] & 255) << 16) | (v3[j] << 24);
                tile[(q * 4 + j) * WPR + cg] = word;
            }
        }
    }
    // fused halo (disjoint bytes from interior writes):
    const i32x4 pad = {(int)0xFDFDFDFD, (int)0xFDFDFDFD, (int)0xFDFDFDFD, (int)0xFDFDFDFD};
    {   // side pads of this row (h+1): w=0 and w=57, 128 B each = 8 x 16B
        int t = threadIdx.x;
        if (t < 16) {
            int w = (t >> 3) ? 57 : 0;
            *(i32x4*)(img + ((size_t)(h + 1) * PH + w) * CIN + (t & 7) * 16) = pad;
        }
    }
    if (h == 0) {       // top pad row 0: 7424 B = 464 x 16B
        for (int t = threadIdx.x; t < 464; t += 256)
            *(i32x4*)(img + (size_t)t * 16) = pad;
    }
    if (h == HH - 1) {  // bottom pad row 57
        for (int t = threadIdx.x; t < 464; t += 256)
            *(i32x4*)(img + (size_t)57 * XP_ROW_BYTES + t * 16) = pad;
    }
    __syncthreads();
    int* dst = (int*)(img + ((size_t)(h + 1) * PH + 1) * CIN);
#pragma unroll
    for (int i = 0; i < 7; ++i) {
        int t = i * 256 + threadIdx.x;
        int w = t >> 5, c4 = t & 31;
        dst[w * 32 + c4] = tile[w * WPR + c4];
    }
}

// ---------------- pack_w: OIHW int32 -> 32x32-fragment-ordered int8 ----------------
// frag f = (tap*4 + kblk)*8 + nf; byte = f*1024 + lane*16 + j
// -> weight[cout = nf*32 + (lane&31)][cin = kblk*32 + (lane>>5)*16 + j][kh][kw]
__global__ __launch_bounds__(256) void pack_w_kernel(const int* __restrict__ w,
                                                     signed char* __restrict__ wq) {
    int idx = blockIdx.x * 256 + threadIdx.x;    // 0..18431
    if (idx >= 9 * 4 * 8 * 64) return;
    int lane = idx & 63;
    int fid = idx >> 6;            // 0..287
    int nf = fid & 7;
    int kblk = (fid >> 3) & 3;
    int t = fid >> 5;              // tap 0..8
    int cout = nf * 32 + (lane & 31);
    int cinb = kblk * 32 + (lane >> 5) * 16;
    int kh = t / 3, kw = t - kh * 3;
    union { signed char b[16]; i32x4 v; } u;
#pragma unroll
    for (int j = 0; j < 16; ++j) {
        int cin = cinb + j;
        u.b[j] = (signed char)w[((cout * CIN + cin) * 3 + kh) * 3 + kw];
    }
    *(i32x4*)(wq + (size_t)idx * 16) = u.v;
}

// ---------------- conv: 32x32x32 implicit GEMM, LDS-A + global-reg-B ----------------
// grid = 1568 blocks x 256 thr: img n (32) x pxblock b (49, 64 px each).
// Block covers 64 px x 256 couts. Wave wv: 64 px x couts [wv*64, +64);
// acc[2][2] of i32x16. Halo = 4 padded rows, XOR-swizzled.
__global__ __launch_bounds__(256) void conv_kernel(const signed char* __restrict__ xq,
                                                   const signed char* __restrict__ wq,
                                                   const int* __restrict__ bias,
                                                   const float* __restrict__ wscale,
                                                   int* __restrict__ out) {
    __shared__ __align__(16) signed char lds[LDS_BYTES];
    const int tid = threadIdx.x;
    const int lane = tid & 63, wv = tid >> 6;     // wv 0..3
    const int col32 = lane & 31, khalf = lane >> 5;

    // XCD-chunked swizzle: 1568 = 8*196; consecutive 196 blocks (4 images) per XCD.
    int orig = (blockIdx.x & 7) * 196 + (blockIdx.x >> 3);
    int n = orig / 49;
    int b = orig - n * 49;
    const int pb = b * 64;                 // first output pixel of block
    const int r0 = pb / 56;                // first output row touched
    const int cbase = pb - r0 * 56;        // column of first pixel (0,8,...,48)

    const signed char* ximg = xq + (size_t)n * XP_IMG_BYTES + (size_t)r0 * XP_ROW_BYTES;

    // ---- prologue: A-halo (4 padded rows, r0-1..r0+2 in orig coords) ----
    // LDS[d] = global[g],  g = d ^ (((d>>7)&7)<<4)
#pragma unroll
    for (int k = 0; k < 8; ++k) {
        int d = k * 4096 + tid * 16;
        if (d < A4_BYTES) {
            int g = d ^ (((d >> 7) & 7) << 4);
            i32x4 v = *(const i32x4*)(ximg + g);
            *(i32x4*)(lds + d) = v;
        }
    }

    // epilogue constants (hoisted)
    float sc[2];
    int b2[2];
#pragma unroll
    for (int nn = 0; nn < 2; ++nn) {
        int cout = wv * 64 + nn * 32 + col32;
        sc[nn] = wscale[cout] * 0.5f;          // 0.05/0.1 * ws
        b2[nn] = 2 * bias[cout];
    }

    __syncthreads();

    // per-m center pixel index in halo (padded coords, rows 0..3 of halo)
    int pm[2];
#pragma unroll
    for (int m = 0; m < 2; ++m) {
        int co = cbase + m * 32 + col32;       // 0..111
        int lr = (co >= 56);
        int c = co - lr * 56;
        pm[m] = (lr + 1) * PH + (c + 1);
    }

    const int tapd[9] = {-PH - 1, -PH, -PH + 1, -1, 0, 1, PH - 1, PH, PH + 1};

    // B direct from global (fragment-ordered, L2-resident), depth-2 ring.
    const signed char* wbase = wq + (size_t)(wv * 2) * 1024 + lane * 16;

    i32x16 acc[2][2] = {};
    i32x4 bn[2][2];
    bn[0][0] = *(const i32x4*)(wbase);
    bn[0][1] = *(const i32x4*)(wbase + 1024);
    bn[1][0] = *(const i32x4*)(wbase + 8192);
    bn[1][1] = *(const i32x4*)(wbase + 8192 + 1024);

#pragma unroll
    for (int s = 0; s < 36; ++s) {
        const int t = s >> 2, kblk = s & 3;
        // A ds_reads (swizzled): cin offset = kblk*32 + khalf*16
        i32x4 a[2];
#pragma unroll
        for (int m = 0; m < 2; ++m) {
            int pix = pm[m] + tapd[t];
            int g = (pix << 7) + (kblk << 5) + (khalf << 4);
            int d = g ^ ((pix & 7) << 4);
            a[m] = *(const i32x4*)(lds + d);
        }
        i32x4 b0 = bn[s & 1][0], b1 = bn[s & 1][1];
        acc[0][0] = __builtin_amdgcn_mfma_i32_32x32x32_i8(a[0], b0, acc[0][0], 0, 0, 0);
        acc[0][1] = __builtin_amdgcn_mfma_i32_32x32x32_i8(a[0], b1, acc[0][1], 0, 0, 0);
        acc[1][0] = __builtin_amdgcn_mfma_i32_32x32x32_i8(a[1], b0, acc[1][0], 0, 0, 0);
        acc[1][1] = __builtin_amdgcn_mfma_i32_32x32x32_i8(a[1], b1, acc[1][1], 0, 0, 0);
        if (s < 34) {   // reissue into just-consumed ring slot for step s+2
            bn[s & 1][0] = *(const i32x4*)(wbase + (size_t)(s + 2) * 8192);
            bn[s & 1][1] = *(const i32x4*)(wbase + (size_t)(s + 2) * 8192 + 1024);
        }
    }

    // ---- epilogue: quantize -> LDS transpose -> contiguous NONTEMPORAL stores ----
    // D map: cout = wv*64 + nn*32 + col32; pixel_local = m*32 + 4*khalf + 8*q + r.
    // Pass p covers couts [p*128, +128) as [cl][64 px] ints, chunk-XOR swizzled:
    // addr_int = cl*64 + (ci ^ (cl&15))*4 + r, ci = pixel chunk (0..15).
    __syncthreads();                     // A-LDS dead
    int* elds = (int*)lds;
    const size_t nbase = (size_t)n * (COUT * PIX_PER_IMG);
#pragma unroll
    for (int p = 0; p < 2; ++p) {
        if ((wv >> 1) == p) {
#pragma unroll
            for (int m = 0; m < 2; ++m) {
#pragma unroll
                for (int nn = 0; nn < 2; ++nn) {
                    int cl = (wv & 1) * 64 + nn * 32 + col32;   // 0..127
#pragma unroll
                    for (int q = 0; q < 4; ++q) {
                        i32x4 v;
#pragma unroll
                        for (int r = 0; r < 4; ++r) {
                            int o = acc[m][nn][q * 4 + r] + b2[nn];
                            float f = fmaf((float)o, sc[nn], 5.0f);
                            f = rintf(f);                 // RNE == jnp.round
                            f = fminf(fmaxf(f, -128.0f), 127.0f);
                            v[r] = (int)f;
                        }
                        int ci = (m * 32 + 4 * khalf + 8 * q) >> 2;   // 0..15
                        *(i32x4*)(elds + cl * 64 + ((ci ^ (cl & 15)) << 2)) = v;
                    }
                }
            }
        }
        __syncthreads();
        // all 4 waves: 2048 tasks = 128 couts x 16 px-quads; nt 16B stores
#pragma unroll
        for (int rnd = 0; rnd < 8; ++rnd) {
            int tg = rnd * 256 + tid;
            int cl = tg >> 4;
            int q = tg & 15;
            i32x4 v = *(const i32x4*)(elds + cl * 64 + (((q ^ (cl & 15))) << 2));
            int cout = p * 128 + cl;
            __builtin_nontemporal_store(v,
                (i32x4*)(out + nbase + (size_t)cout * PIX_PER_IMG + pb + q * 4));
        }
        __syncthreads();
    }
}

extern "C" void kernel_launch(void* const* d_in, const int* in_sizes, int n_in,
                              void* d_out, int out_size, void* d_ws, size_t ws_size,
                              hipStream_t stream) {
    const int* x = (const int*)d_in[0];
    const int* w = (const int*)d_in[1];
    const int* bias = (const int*)d_in[2];
    const float* ws = (const float*)d_in[3];
    int* out = (int*)d_out;

    signed char* xq = (signed char*)d_ws;                 // padded NHWC int8
    signed char* wq = xq + XQ_PAD_BYTES;                  // 288 KB fragment-ordered weights

    pack_x_kernel<<<NB_N * HH, 256, 0, stream>>>(x, xq);  // halo fused in
    pack_w_kernel<<<72, 256, 0, stream>>>(w, wq);
    conv_kernel<<<1568, 256, 0, stream>>>(xq, wq, bias, ws, out);
}

// Round 22
// 63.833 us; speedup vs baseline: 1.2138x; 1.2138x over previous
//
#include <hip/hip_runtime.h>

// QuantizedConv2d: N=32, CIN=128, H=W=56, COUT=256, 3x3, pad=1 (zp=-3), stride 1.
// Round 22: r21's 32x32x32 structure with CONFLICT-FREE layouts (r21 diagnosed:
// 2.3M bank-conflict cycles from 4-way A-reads + 4-8-way epilogue).
//  (1) A in LDS is cin-chunk-major [c=cin/16][pixel], stride 3728B (bank +4/chunk):
//      each half-wave A-read = contiguous 512B run (lane=pixel) -> 0 conflicts;
//      taps shift the run start. Staging global reads fully coalesced.
//  (2) Epilogue buffer stride 68 ints/cout-row (r15 idiom) -> staggered runs.
// Keep: 64px x 256cout blocks (FETCH 8MB), depth-2 B ring, nt stores, (256,3).

typedef __attribute__((ext_vector_type(4))) int i32x4;
typedef __attribute__((ext_vector_type(16))) int i32x16;

#define NB_N 32
#define CIN 128
#define HH 56
#define WW 56
#define PH 58                              // padded H/W
#define COUT 256
#define PIX_PER_IMG (HH*WW)                // 3136
#define X_IMG_INTS (PIX_PER_IMG*CIN)
#define XP_ROW_BYTES (PH*CIN)              // 7424
#define XP_IMG_BYTES (PH*XP_ROW_BYTES)     // 430592
#define XQ_PAD_BYTES ((size_t)NB_N*XP_IMG_BYTES)
#define CH_STRIDE 3728                     // bytes per cin-chunk plane (232px*16 + 16 pad)
#define A_SLOTS 1856                       // 8 chunks * 232 px (16B each)
#define EP_STRIDE 68                       // ints per cout row in epilogue LDS
#define LDS_BYTES 34816                    // max(8*3728=29824, 128*68*4=34816)

// ---------------- pack_x: NCHW int32 -> padded NHWC int8 (+ fused halo) ----------------
#define WPR 33   // words per w-row (132 B)
__global__ __launch_bounds__(256) void pack_x_kernel(const int* __restrict__ x,
                                                     signed char* __restrict__ xq) {
    __shared__ int tile[WW * WPR];           // 7392 B
    int nh = blockIdx.x;                     // 0..N*H-1
    int n = nh / HH, h = nh - n * HH;
    const int* src = x + (size_t)n * X_IMG_INTS + h * WW;  // (n, c, h, 0)
    signed char* img = xq + (size_t)n * XP_IMG_BYTES;
    int q = threadIdx.x & 15;                // w-quad (0..13 valid)
    int cg4 = threadIdx.x >> 4;              // 0..15
    if (q < 14) {
#pragma unroll
        for (int i = 0; i < 2; ++i) {
            int cg = cg4 + i * 16;           // channel group 0..31
            i32x4 v0 = *(const i32x4*)(src + (cg * 4 + 0) * PIX_PER_IMG + q * 4);
            i32x4 v1 = *(const i32x4*)(src + (cg * 4 + 1) * PIX_PER_IMG + q * 4);
            i32x4 v2 = *(const i32x4*)(src + (cg * 4 + 2) * PIX_PER_IMG + q * 4);
            i32x4 v3 = *(const i32x4*)(src + (cg * 4 + 3) * PIX_PER_IMG + q * 4);
#pragma unroll
            for (int j = 0; j < 4; ++j) {
                int word = (v0[j] & 255) | ((v1[j] & 255) << 8) |
                           ((v2[j] & 255) << 16) | (v3[j] << 24);
                tile[(q * 4 + j) * WPR + cg] = word;
            }
        }
    }
    // fused halo (disjoint bytes from interior writes):
    const i32x4 pad = {(int)0xFDFDFDFD, (int)0xFDFDFDFD, (int)0xFDFDFDFD, (int)0xFDFDFDFD};
    {   // side pads of this row (h+1): w=0 and w=57, 128 B each = 8 x 16B
        int t = threadIdx.x;
        if (t < 16) {
            int w = (t >> 3) ? 57 : 0;
            *(i32x4*)(img + ((size_t)(h + 1) * PH + w) * CIN + (t & 7) * 16) = pad;
        }
    }
    if (h == 0) {       // top pad row 0
        for (int t = threadIdx.x; t < 464; t += 256)
            *(i32x4*)(img + (size_t)t * 16) = pad;
    }
    if (h == HH - 1) {  // bottom pad row 57
        for (int t = threadIdx.x; t < 464; t += 256)
            *(i32x4*)(img + (size_t)57 * XP_ROW_BYTES + t * 16) = pad;
    }
    __syncthreads();
    int* dst = (int*)(img + ((size_t)(h + 1) * PH + 1) * CIN);
#pragma unroll
    for (int i = 0; i < 7; ++i) {
        int t = i * 256 + threadIdx.x;
        int w = t >> 5, c4 = t & 31;
        dst[w * 32 + c4] = tile[w * WPR + c4];
    }
}

// ---------------- pack_w: OIHW int32 -> 32x32-fragment-ordered int8 ----------------
// frag f = (tap*4 + kblk)*8 + nf; byte = f*1024 + lane*16 + j
// -> weight[cout = nf*32 + (lane&31)][cin = kblk*32 + (lane>>5)*16 + j][kh][kw]
__global__ __launch_bounds__(256) void pack_w_kernel(const int* __restrict__ w,
                                                     signed char* __restrict__ wq) {
    int idx = blockIdx.x * 256 + threadIdx.x;    // 0..18431
    if (idx >= 9 * 4 * 8 * 64) return;
    int lane = idx & 63;
    int fid = idx >> 6;            // 0..287
    int nf = fid & 7;
    int kblk = (fid >> 3) & 3;
    int t = fid >> 5;              // tap 0..8
    int cout = nf * 32 + (lane & 31);
    int cinb = kblk * 32 + (lane >> 5) * 16;
    int kh = t / 3, kw = t - kh * 3;
    union { signed char b[16]; i32x4 v; } u;
#pragma unroll
    for (int j = 0; j < 16; ++j) {
        int cin = cinb + j;
        u.b[j] = (signed char)w[((cout * CIN + cin) * 3 + kh) * 3 + kw];
    }
    *(i32x4*)(wq + (size_t)idx * 16) = u.v;
}

// ---------------- conv: 32x32x32 implicit GEMM, chunk-major LDS-A ----------------
// grid = 1568 blocks x 256 thr: img n (32) x pxblock b (49, 64 px each).
// Block covers 64 px x 256 couts. Wave wv: 64 px x couts [wv*64, +64);
// acc[2][2] of i32x16.
__global__ __launch_bounds__(256, 3) void conv_kernel(const signed char* __restrict__ xq,
                                                      const signed char* __restrict__ wq,
                                                      const int* __restrict__ bias,
                                                      const float* __restrict__ wscale,
                                                      int* __restrict__ out) {
    __shared__ __align__(16) signed char lds[LDS_BYTES];
    const int tid = threadIdx.x;
    const int lane = tid & 63, wv = tid >> 6;     // wv 0..3
    const int col32 = lane & 31, khalf = lane >> 5;

    // XCD-chunked swizzle: 1568 = 8*196; consecutive 196 blocks (4 images) per XCD.
    int orig = (blockIdx.x & 7) * 196 + (blockIdx.x >> 3);
    int n = orig / 49;
    int b = orig - n * 49;
    const int pb = b * 64;                 // first output pixel of block
    const int r0 = pb / 56;                // first output row touched
    const int cbase = pb - r0 * 56;        // column of first pixel

    // halo window: padded rows r0..r0+3 (= orig rows r0-1..r0+2), 29696B contiguous
    const signed char* ximg = xq + (size_t)n * XP_IMG_BYTES + (size_t)r0 * XP_ROW_BYTES;

    // ---- prologue: stage halo into chunk-major LDS: lds[c*CH_STRIDE + pix*16] ----
    // slot s: c = s&7 (cin chunk), pix = s>>3 (0..231). Global = pix*128 + c*16
    // -> 8 consecutive lanes read 128B contiguous (fully coalesced).
#pragma unroll
    for (int k = 0; k < 8; ++k) {
        int s = k * 256 + tid;
        if (s < A_SLOTS) {
            int c = s & 7, pix = s >> 3;
            i32x4 v = *(const i32x4*)(ximg + pix * 128 + c * 16);
            *(i32x4*)(lds + c * CH_STRIDE + pix * 16) = v;
        }
    }

    // epilogue constants (hoisted)
    float sc[2];
    int b2[2];
#pragma unroll
    for (int nn = 0; nn < 2; ++nn) {
        int cout = wv * 64 + nn * 32 + col32;
        sc[nn] = wscale[cout] * 0.5f;          // 0.05/0.1 * ws
        b2[nn] = 2 * bias[cout];
    }

    __syncthreads();

    // per-m center pixel (halo coords: row 1..2, 58 px/row)
    int pm[2];
#pragma unroll
    for (int m = 0; m < 2; ++m) {
        int co = cbase + m * 32 + col32;       // 0..111
        int lr = (co >= 56);
        int c = co - lr * 56;
        pm[m] = (lr + 1) * PH + (c + 1);       // pixel index in 4x58 halo
    }

    const int tapd[9] = {-PH - 1, -PH, -PH + 1, -1, 0, 1, PH - 1, PH, PH + 1};

    // B direct from global (fragment-ordered, L2-resident), depth-2 ring.
    const signed char* wbase = wq + (size_t)(wv * 2) * 1024 + lane * 16;

    i32x16 acc[2][2] = {};
    i32x4 bn[2][2];
    bn[0][0] = *(const i32x4*)(wbase);
    bn[0][1] = *(const i32x4*)(wbase + 1024);
    bn[1][0] = *(const i32x4*)(wbase + 8192);
    bn[1][1] = *(const i32x4*)(wbase + 8192 + 1024);

#pragma unroll
    for (int s = 0; s < 36; ++s) {
        const int t = s >> 2, kblk = s & 3;
        const int chunk = kblk * 2 + khalf;
        // A ds_reads: contiguous 512B run per half-wave (lane = pixel) -> 0 conflicts
        i32x4 a[2];
#pragma unroll
        for (int m = 0; m < 2; ++m) {
            int pix = pm[m] + tapd[t];
            a[m] = *(const i32x4*)(lds + chunk * CH_STRIDE + pix * 16);
        }
        i32x4 b0 = bn[s & 1][0], b1 = bn[s & 1][1];
        acc[0][0] = __builtin_amdgcn_mfma_i32_32x32x32_i8(a[0], b0, acc[0][0], 0, 0, 0);
        acc[0][1] = __builtin_amdgcn_mfma_i32_32x32x32_i8(a[0], b1, acc[0][1], 0, 0, 0);
        acc[1][0] = __builtin_amdgcn_mfma_i32_32x32x32_i8(a[1], b0, acc[1][0], 0, 0, 0);
        acc[1][1] = __builtin_amdgcn_mfma_i32_32x32x32_i8(a[1], b1, acc[1][1], 0, 0, 0);
        if (s < 34) {   // reissue into just-consumed ring slot for step s+2
            bn[s & 1][0] = *(const i32x4*)(wbase + (size_t)(s + 2) * 8192);
            bn[s & 1][1] = *(const i32x4*)(wbase + (size_t)(s + 2) * 8192 + 1024);
        }
    }

    // ---- epilogue: quantize -> LDS (stride-68 rows) -> contiguous nt stores ----
    // D map: cout = wv*64 + nn*32 + col32; px_local(reg j) = m*32 + (j&3) + 8*(j>>2) + 4*khalf.
    __syncthreads();                     // A-LDS dead
    int* elds = (int*)lds;
    const size_t nbase = (size_t)n * (COUT * PIX_PER_IMG);
#pragma unroll
    for (int p = 0; p < 2; ++p) {
        if ((wv >> 1) == p) {
#pragma unroll
            for (int m = 0; m < 2; ++m) {
#pragma unroll
                for (int nn = 0; nn < 2; ++nn) {
                    int cl = (wv & 1) * 64 + nn * 32 + col32;   // 0..127
#pragma unroll
                    for (int q = 0; q < 4; ++q) {
                        i32x4 v;
#pragma unroll
                        for (int r = 0; r < 4; ++r) {
                            int o = acc[m][nn][q * 4 + r] + b2[nn];
                            float f = fmaf((float)o, sc[nn], 5.0f);
                            f = rintf(f);                 // RNE == jnp.round
                            f = fminf(fmaxf(f, -128.0f), 127.0f);
                            v[r] = (int)f;
                        }
                        *(i32x4*)(elds + cl * EP_STRIDE + m * 32 + 8 * q + 4 * khalf) = v;
                    }
                }
            }
        }
        __syncthreads();
        // all 4 waves: 2048 tasks = 128 couts x 16 px-quads; contiguous runs per cout
#pragma unroll
        for (int rnd = 0; rnd < 8; ++rnd) {
            int tg = rnd * 256 + tid;
            int cl = tg >> 4;          // cout row (16 lanes sweep its 256B contiguously)
            int q = tg & 15;
            i32x4 v = *(const i32x4*)(elds + cl * EP_STRIDE + q * 4);
            int cout = p * 128 + cl;
            __builtin_nontemporal_store(v,
                (i32x4*)(out + nbase + (size_t)cout * PIX_PER_IMG + pb + q * 4));
        }
        __syncthreads();
    }
}

extern "C" void kernel_launch(void* const* d_in, const int* in_sizes, int n_in,
                              void* d_out, int out_size, void* d_ws, size_t ws_size,
                              hipStream_t stream) {
    const int* x = (const int*)d_in[0];
    const int* w = (const int*)d_in[1];
    const int* bias = (const int*)d_in[2];
    const float* ws = (const float*)d_in[3];
    int* out = (int*)d_out;

    signed char* xq = (signed char*)d_ws;                 // padded NHWC int8
    signed char* wq = xq + XQ_PAD_BYTES;                  // 288 KB fragment-ordered weights

    pack_x_kernel<<<NB_N * HH, 256, 0, stream>>>(x, xq);  // halo fused in
    pack_w_kernel<<<72, 256, 0, stream>>>(w, wq);
    conv_kernel<<<1568, 256, 0, stream>>>(xq, wq, bias, ws, out);
}